// Round 1
// baseline (169.701 us; speedup 1.0000x reference)
//
#include <hip/hip_runtime.h>

#define NTOK 8192
#define DH 128

typedef __attribute__((ext_vector_type(8))) short bf16x8;
typedef __attribute__((ext_vector_type(4))) float f32x4;
typedef __attribute__((ext_vector_type(4))) unsigned short u16x4;

static __device__ __forceinline__ unsigned short f2bf(float x) {
  union { float f; unsigned int u; } a; a.f = x;
  unsigned int r = a.u + 0x7FFFu + ((a.u >> 16) & 1u);  // RNE
  return (unsigned short)(r >> 16);
}

// Flash attention forward, swapped-QK^T formulation.
// Each block: 64 Q rows (4 waves x 16), iterates over a KV chunk of
// chunk_len, staging K (64x128, swizzled) and V^T (128x64, swizzled) in LDS.
// Writes unnormalized O^T partials + per-row (m, l) in log2 units.
__global__ __launch_bounds__(256, 2)
void fa_fwd(const float* __restrict__ Qg, const float* __restrict__ Kg,
            const float* __restrict__ Vg, float* __restrict__ Od,
            float* __restrict__ Mp, float* __restrict__ Lp,
            int ksplit, int chunk_len)
{
  __shared__ __align__(16) char smem[32768];
  char* smK = smem;            // K tile: rows kv 0..63, 256B/row (bf16), XOR ((row&7)<<4)
  char* smV = smem + 16384;    // V^T:    rows d 0..127, 128B/row (bf16), XOR ((d&15)<<3)

  const int tid  = threadIdx.x;
  const int lane = tid & 63;
  const int wv   = tid >> 6;
  const int l15  = lane & 15;
  const int lg   = lane >> 4;

  const int q0    = blockIdx.x * 64 + wv * 16;
  const int chunk = blockIdx.y;

  const float QSCALE = 0.1275313310087464f;  // rsqrt(128) * log2(e)

  // ---- Q fragments (once). k-convention for QK^T: k = lg*8 + j (both operands).
  bf16x8 qf[4];
  {
    const float* qsrc = Qg + (size_t)(q0 + l15) * DH + lg * 8;
    #pragma unroll
    for (int dm = 0; dm < 4; ++dm) {
      union { bf16x8 v; unsigned short u[8]; } f;
      #pragma unroll
      for (int j = 0; j < 8; ++j) f.u[j] = f2bf(qsrc[dm * 32 + j] * QSCALE);
      qf[dm] = f.v;
    }
  }

  float m_run = -INFINITY;
  float l_run = 0.f;
  f32x4 oacc[8];
  #pragma unroll
  for (int i = 0; i < 8; ++i) oacc[i] = (f32x4){0.f, 0.f, 0.f, 0.f};

  const int kv_begin = chunk * chunk_len;
  const int nsteps   = chunk_len / 64;

  const int krow = tid >> 2;        // 0..63  (K staging row)
  const int kcg  = (tid & 3) * 32;  // 32 floats per thread

  for (int step = 0; step < nsteps; ++step) {
    const int kvb = kv_begin + step * 64;
    __syncthreads();

    // ---- stage K tile (64 kv x 128 d), fp32 -> bf16, swizzled rows
    {
      const float* src = Kg + (size_t)(kvb + krow) * DH + kcg;
      const int sw = (krow & 7) << 4;
      #pragma unroll
      for (int w = 0; w < 4; ++w) {
        float4 a = *reinterpret_cast<const float4*>(src + w * 8);
        float4 b = *reinterpret_cast<const float4*>(src + w * 8 + 4);
        union { bf16x8 v; unsigned short u[8]; } f;
        f.u[0] = f2bf(a.x); f.u[1] = f2bf(a.y); f.u[2] = f2bf(a.z); f.u[3] = f2bf(a.w);
        f.u[4] = f2bf(b.x); f.u[5] = f2bf(b.y); f.u[6] = f2bf(b.z); f.u[7] = f2bf(b.w);
        int colb = kcg * 2 + w * 16;
        *reinterpret_cast<bf16x8*>(smK + krow * 256 + (colb ^ sw)) = f.v;
      }
    }

    // ---- stage V^T (128 d x 64 kv): 4x4 register transpose per task
    {
      #pragma unroll
      for (int it = 0; it < 2; ++it) {
        int task = tid + it * 256;        // 512 tasks of 4kv x 4d
        int kvl  = (task & 15) * 4;
        int d0   = (task >> 4) * 4;
        const float* src = Vg + (size_t)(kvb + kvl) * DH + d0;
        float4 r0 = *reinterpret_cast<const float4*>(src);
        float4 r1 = *reinterpret_cast<const float4*>(src + DH);
        float4 r2 = *reinterpret_cast<const float4*>(src + 2 * DH);
        float4 r3 = *reinterpret_cast<const float4*>(src + 3 * DH);
        const int baseb = kvl * 2;
        { int d = d0 + 0;
          u16x4 w4 = (u16x4){f2bf(r0.x), f2bf(r1.x), f2bf(r2.x), f2bf(r3.x)};
          *reinterpret_cast<u16x4*>(smV + d * 128 + (baseb ^ ((d & 15) << 3))) = w4; }
        { int d = d0 + 1;
          u16x4 w4 = (u16x4){f2bf(r0.y), f2bf(r1.y), f2bf(r2.y), f2bf(r3.y)};
          *reinterpret_cast<u16x4*>(smV + d * 128 + (baseb ^ ((d & 15) << 3))) = w4; }
        { int d = d0 + 2;
          u16x4 w4 = (u16x4){f2bf(r0.z), f2bf(r1.z), f2bf(r2.z), f2bf(r3.z)};
          *reinterpret_cast<u16x4*>(smV + d * 128 + (baseb ^ ((d & 15) << 3))) = w4; }
        { int d = d0 + 3;
          u16x4 w4 = (u16x4){f2bf(r0.w), f2bf(r1.w), f2bf(r2.w), f2bf(r3.w)};
          *reinterpret_cast<u16x4*>(smV + d * 128 + (baseb ^ ((d & 15) << 3))) = w4; }
      }
    }
    __syncthreads();

    // ---- QK^T: S^T tiles (kv rows, q cols). A = K tile, B = Q frags.
    f32x4 st[4];
    #pragma unroll
    for (int kt = 0; kt < 4; ++kt) st[kt] = (f32x4){0.f, 0.f, 0.f, 0.f};
    #pragma unroll
    for (int kt = 0; kt < 4; ++kt) {
      const int row = kt * 16 + l15;
      const int rs  = row * 256;
      const int sw  = (row & 7) << 4;
      #pragma unroll
      for (int dm = 0; dm < 4; ++dm) {
        int colb = dm * 64 + lg * 16;
        bf16x8 a = *reinterpret_cast<const bf16x8*>(smK + rs + (colb ^ sw));
        st[kt] = __builtin_amdgcn_mfma_f32_16x16x32_bf16(a, qf[dm], st[kt], 0, 0, 0);
      }
    }

    // ---- online softmax (scores in log2 units; lane owns q = q0 + l15)
    float p[16];
    float pmax = -INFINITY;
    #pragma unroll
    for (int kt = 0; kt < 4; ++kt) {
      pmax = fmaxf(pmax, st[kt][0]); pmax = fmaxf(pmax, st[kt][1]);
      pmax = fmaxf(pmax, st[kt][2]); pmax = fmaxf(pmax, st[kt][3]);
    }
    pmax = fmaxf(pmax, __shfl_xor(pmax, 16));
    pmax = fmaxf(pmax, __shfl_xor(pmax, 32));
    const float m_new = fmaxf(m_run, pmax);
    const float corr  = exp2f(m_run - m_new);
    float psum = 0.f;
    #pragma unroll
    for (int kt = 0; kt < 4; ++kt) {
      #pragma unroll
      for (int r = 0; r < 4; ++r) {
        float e = exp2f(st[kt][r] - m_new);
        p[kt * 4 + r] = e;
        psum += e;
      }
    }
    psum += __shfl_xor(psum, 16);
    psum += __shfl_xor(psum, 32);
    l_run = l_run * corr + psum;
    m_run = m_new;
    #pragma unroll
    for (int i = 0; i < 8; ++i) oacc[i] = oacc[i] * corr;

    // ---- pack P fragments. k-convention for PV: k = lg*4 + (j&3) + 16*(j>>2),
    //      matching the C/D register layout of st (no cross-lane moves needed).
    bf16x8 pf0, pf1;
    {
      union { bf16x8 v; unsigned short u[8]; } f;
      f.u[0] = f2bf(p[0]);  f.u[1] = f2bf(p[1]);  f.u[2] = f2bf(p[2]);  f.u[3] = f2bf(p[3]);
      f.u[4] = f2bf(p[4]);  f.u[5] = f2bf(p[5]);  f.u[6] = f2bf(p[6]);  f.u[7] = f2bf(p[7]);
      pf0 = f.v;
      f.u[0] = f2bf(p[8]);  f.u[1] = f2bf(p[9]);  f.u[2] = f2bf(p[10]); f.u[3] = f2bf(p[11]);
      f.u[4] = f2bf(p[12]); f.u[5] = f2bf(p[13]); f.u[6] = f2bf(p[14]); f.u[7] = f2bf(p[15]);
      pf1 = f.v;
    }

    // ---- PV: O^T += V^T · P. A = V^T frag (same k-convention), B = P frag.
    #pragma unroll
    for (int h2 = 0; h2 < 2; ++h2) {
      const bf16x8 pb = h2 ? pf1 : pf0;
      const int c0 = h2 * 64 + lg * 8;
      #pragma unroll
      for (int dt = 0; dt < 8; ++dt) {
        const int d  = dt * 16 + l15;
        const int sw = (d & 15) << 3;
        union { bf16x8 v; u16x4 h[2]; } a;
        a.h[0] = *reinterpret_cast<const u16x4*>(smV + d * 128 + (c0 ^ sw));
        a.h[1] = *reinterpret_cast<const u16x4*>(smV + d * 128 + ((c0 + 32) ^ sw));
        oacc[dt] = __builtin_amdgcn_mfma_f32_16x16x32_bf16(a.v, pb, oacc[dt], 0, 0, 0);
      }
    }
  }

  // ---- epilogue. O^T layout: d = dt*16 + lg*4 + r, q = q0 + l15.
  const int qg = q0 + l15;
  if (ksplit == 1) {
    const float inv = 1.f / l_run;
    #pragma unroll
    for (int dt = 0; dt < 8; ++dt) {
      #pragma unroll
      for (int r = 0; r < 4; ++r)
        Od[(size_t)qg * DH + dt * 16 + lg * 4 + r] = oacc[dt][r] * inv;
    }
  } else {
    float* dst = Od + (size_t)chunk * NTOK * DH;
    #pragma unroll
    for (int dt = 0; dt < 8; ++dt) {
      #pragma unroll
      for (int r = 0; r < 4; ++r)
        dst[(size_t)qg * DH + dt * 16 + lg * 4 + r] = oacc[dt][r];
    }
    if (lane < 16) {
      Mp[chunk * NTOK + qg] = m_run;
      Lp[chunk * NTOK + qg] = l_run;
    }
  }
}

__global__ __launch_bounds__(256)
void fa_combine(const float* __restrict__ Op, const float* __restrict__ Mp,
                const float* __restrict__ Lp, float* __restrict__ out, int ksplit)
{
  const int gid = blockIdx.x * 256 + threadIdx.x;   // N*D/4 threads
  const int q   = gid >> 5;
  const int dv  = (gid & 31) * 4;
  float mx = -INFINITY;
  for (int c = 0; c < ksplit; ++c) mx = fmaxf(mx, Mp[c * NTOK + q]);
  float den = 0.f;
  float ax = 0.f, ay = 0.f, az = 0.f, aw = 0.f;
  for (int c = 0; c < ksplit; ++c) {
    const float w = exp2f(Mp[c * NTOK + q] - mx);
    den += w * Lp[c * NTOK + q];
    float4 o = *reinterpret_cast<const float4*>(Op + (size_t)c * NTOK * DH + (size_t)q * DH + dv);
    ax += w * o.x; ay += w * o.y; az += w * o.z; aw += w * o.w;
  }
  const float r = 1.f / den;
  float4 res; res.x = ax * r; res.y = ay * r; res.z = az * r; res.w = aw * r;
  *reinterpret_cast<float4*>(out + (size_t)q * DH + dv) = res;
}

extern "C" void kernel_launch(void* const* d_in, const int* in_sizes, int n_in,
                              void* d_out, int out_size, void* d_ws, size_t ws_size,
                              hipStream_t stream)
{
  const float* Q = (const float*)d_in[0];
  const float* K = (const float*)d_in[1];
  const float* V = (const float*)d_in[2];
  float* out = (float*)d_out;

  auto need = [](int ks) {
    return (size_t)ks * NTOK * DH * 4 + (size_t)2 * ks * NTOK * 4;
  };
  int KS = 1;
  if      (ws_size >= need(4)) KS = 4;
  else if (ws_size >= need(2)) KS = 2;

  float* Op = (float*)d_ws;
  float* Mp = Op + (size_t)KS * NTOK * DH;
  float* Lp = Mp + (size_t)KS * NTOK;

  dim3 grid(NTOK / 64, KS);
  if (KS == 1) {
    fa_fwd<<<grid, 256, 0, stream>>>(Q, K, V, out, Mp, Lp, 1, NTOK);
  } else {
    fa_fwd<<<grid, 256, 0, stream>>>(Q, K, V, Op, Mp, Lp, KS, NTOK / KS);
    fa_combine<<<NTOK * DH / 4 / 256, 256, 0, stream>>>(Op, Mp, Lp, out, KS);
  }
}

// Round 2
// 79.649 us; speedup vs baseline: 2.1306x; 2.1306x over previous
//
#include <hip/hip_runtime.h>

#define NTOK 8192
#define DH   128
#define QBLK 128
#define KVB  64

typedef __attribute__((ext_vector_type(8)))  short bf16x8;
typedef __attribute__((ext_vector_type(16))) float f32x16;
typedef __attribute__((ext_vector_type(4)))  unsigned short u16x4;

typedef __attribute__((address_space(1))) const void gv_t;
typedef __attribute__((address_space(3))) void sv_t;

static __device__ __forceinline__ unsigned short f2bf(float x) {
  union { float f; unsigned int u; } a; a.f = x;
  unsigned int r = a.u + 0x7FFFu + ((a.u >> 16) & 1u);  // RNE
  return (unsigned short)(r >> 16);
}

static __device__ __forceinline__ f32x16 zero16() {
  f32x16 v;
  #pragma unroll
  for (int i = 0; i < 16; ++i) v[i] = 0.f;
  return v;
}

// ---------------------------------------------------------------------------
// Pre-pass: build bf16 "LDS images" of K (row-major, swizzled (row&15)<<4 at
// 16B granularity) and V^T (128 d-rows x 128B, swizzled (d&15)<<3 at 8B
// granularity), tiled by 64 kv rows (16KB per tile per image). fa_fwd then
// stages tiles with linear global_load_lds DMA.
// ---------------------------------------------------------------------------
__global__ __launch_bounds__(256)
void fa_prep(const float* __restrict__ Kg, const float* __restrict__ Vg,
             char* __restrict__ Kimg, char* __restrict__ Vimg)
{
  const int t = blockIdx.x;
  const int tid = threadIdx.x;

  { // K tile: 64 rows x 256B
    const int krow = tid >> 2;
    const int kcg  = (tid & 3) * 32;
    const float* src = Kg + ((size_t)t * KVB + krow) * DH + kcg;
    char* drow = Kimg + (size_t)t * 16384 + krow * 256;
    const int sw = (krow & 15) << 4;
    #pragma unroll
    for (int w = 0; w < 4; ++w) {
      float4 a = *reinterpret_cast<const float4*>(src + w * 8);
      float4 b = *reinterpret_cast<const float4*>(src + w * 8 + 4);
      union { bf16x8 v; unsigned short u[8]; } f;
      f.u[0] = f2bf(a.x); f.u[1] = f2bf(a.y); f.u[2] = f2bf(a.z); f.u[3] = f2bf(a.w);
      f.u[4] = f2bf(b.x); f.u[5] = f2bf(b.y); f.u[6] = f2bf(b.z); f.u[7] = f2bf(b.w);
      *reinterpret_cast<bf16x8*>(drow + ((kcg * 2 + w * 16) ^ sw)) = f.v;
    }
  }

  { // V^T tile: 128 d-rows x 128B, 4x4 register transpose per task
    #pragma unroll
    for (int it = 0; it < 2; ++it) {
      int task = tid + it * 256;            // 512 tasks of 4kv x 4d
      int kvl  = (task & 15) * 4;
      int d0   = (task >> 4) * 4;
      const float* src = Vg + ((size_t)t * KVB + kvl) * DH + d0;
      float4 r0 = *reinterpret_cast<const float4*>(src);
      float4 r1 = *reinterpret_cast<const float4*>(src + DH);
      float4 r2 = *reinterpret_cast<const float4*>(src + 2 * DH);
      float4 r3 = *reinterpret_cast<const float4*>(src + 3 * DH);
      char* base = Vimg + (size_t)t * 16384;
      const int bb = kvl * 2;
      { int d = d0 + 0;
        u16x4 w4 = (u16x4){f2bf(r0.x), f2bf(r1.x), f2bf(r2.x), f2bf(r3.x)};
        *reinterpret_cast<u16x4*>(base + d * 128 + (bb ^ ((d & 15) << 3))) = w4; }
      { int d = d0 + 1;
        u16x4 w4 = (u16x4){f2bf(r0.y), f2bf(r1.y), f2bf(r2.y), f2bf(r3.y)};
        *reinterpret_cast<u16x4*>(base + d * 128 + (bb ^ ((d & 15) << 3))) = w4; }
      { int d = d0 + 2;
        u16x4 w4 = (u16x4){f2bf(r0.z), f2bf(r1.z), f2bf(r2.z), f2bf(r3.z)};
        *reinterpret_cast<u16x4*>(base + d * 128 + (bb ^ ((d & 15) << 3))) = w4; }
      { int d = d0 + 3;
        u16x4 w4 = (u16x4){f2bf(r0.w), f2bf(r1.w), f2bf(r2.w), f2bf(r3.w)};
        *reinterpret_cast<u16x4*>(base + d * 128 + (bb ^ ((d & 15) << 3))) = w4; }
    }
  }
}

// ---------------------------------------------------------------------------
// Flash fwd: 4 waves x 32 q each (QBLK=128), 32x32x16 MFMA, double-buffered
// DMA staging. Swapped QK^T (S^T = K*Q) keeps softmax lane-local per q-col.
// ---------------------------------------------------------------------------
__global__ __launch_bounds__(256, 2)
void fa_fwd(const float* __restrict__ Qg, const char* __restrict__ Kimg,
            const char* __restrict__ Vimg, float* __restrict__ Od,
            float* __restrict__ Mp, float* __restrict__ Lp,
            int ksplit, int chunk_len)
{
  __shared__ __align__(16) char smem[2][32768];   // [buf][K 16KB | V 16KB]
  const int tid  = threadIdx.x;
  const int lane = tid & 63;
  const int wv   = tid >> 6;
  const int l31  = lane & 31;
  const int hi   = lane >> 5;

  const int q     = blockIdx.x * QBLK + wv * 32 + l31;
  const int chunk = blockIdx.y;
  const float QSCALE = 0.1275313310087464f;       // rsqrt(128) * log2(e)

  const int tile0 = (chunk * chunk_len) >> 6;
  const int nst   = chunk_len >> 6;

  // Per-wave DMA: waves 0,1 copy K halves; waves 2,3 copy V halves (8KB each).
  const char* gbase = (wv < 2 ? Kimg : Vimg);
  const size_t goff = (size_t)(wv & 1) * 8192 + (size_t)lane * 16;
  const int    loff = (wv < 2 ? 0 : 16384) + (wv & 1) * 8192;

#define STAGE(B, T) do {                                                      \
    const char* _s = gbase + (size_t)(T) * 16384 + goff;                      \
    char* _d = &smem[B][loff];                                                \
    _Pragma("unroll")                                                         \
    for (int _i = 0; _i < 8; ++_i)                                            \
      __builtin_amdgcn_global_load_lds((gv_t*)(_s + _i * 1024),               \
                                       (sv_t*)(_d + _i * 1024), 16, 0, 0);    \
  } while (0)

  STAGE(0, tile0);

  // Q fragments: qf[kc] holds Q[q][kc*16 + hi*8 + j], pre-scaled.
  bf16x8 qf[8];
  {
    const float* qs = Qg + (size_t)q * DH + hi * 8;
    #pragma unroll
    for (int kc = 0; kc < 8; ++kc) {
      float4 a = *reinterpret_cast<const float4*>(qs + kc * 16);
      float4 b = *reinterpret_cast<const float4*>(qs + kc * 16 + 4);
      union { bf16x8 v; unsigned short u[8]; } f;
      f.u[0] = f2bf(a.x * QSCALE); f.u[1] = f2bf(a.y * QSCALE);
      f.u[2] = f2bf(a.z * QSCALE); f.u[3] = f2bf(a.w * QSCALE);
      f.u[4] = f2bf(b.x * QSCALE); f.u[5] = f2bf(b.y * QSCALE);
      f.u[6] = f2bf(b.z * QSCALE); f.u[7] = f2bf(b.w * QSCALE);
      qf[kc] = f.v;
    }
  }

  f32x16 oacc[4];
  #pragma unroll
  for (int i = 0; i < 4; ++i) oacc[i] = zero16();
  float m_run = -INFINITY, l_run = 0.f;

  __syncthreads();                                 // tile 0 ready (drains DMA)

  int cur = 0;
  for (int t = 0; t < nst; ++t) {
    if (t + 1 < nst) STAGE(cur ^ 1, tile0 + t + 1);   // overlaps compute below

    const char* smK = smem[cur];
    const char* smV = smem[cur] + 16384;

    // ---- QK^T: S^T (64 kv x 32 q) = two 32x32 tiles, K dim = 128.
    f32x16 st0 = zero16(), st1 = zero16();
    const int swk = (l31 & 15) << 4;
    #pragma unroll
    for (int kc = 0; kc < 8; ++kc) {
      const int cb = kc * 32 + hi * 16;
      bf16x8 a0 = *reinterpret_cast<const bf16x8*>(smK + l31 * 256 + (cb ^ swk));
      bf16x8 a1 = *reinterpret_cast<const bf16x8*>(smK + (l31 + 32) * 256 + (cb ^ swk));
      st0 = __builtin_amdgcn_mfma_f32_32x32x16_bf16(a0, qf[kc], st0, 0, 0, 0);
      st1 = __builtin_amdgcn_mfma_f32_32x32x16_bf16(a1, qf[kc], st1, 0, 0, 0);
    }

    // ---- online softmax (log2 domain). Lane owns q; partner lane is +32.
    float pmax = -INFINITY;
    #pragma unroll
    for (int r = 0; r < 16; ++r) pmax = fmaxf(pmax, fmaxf(st0[r], st1[r]));
    pmax = fmaxf(pmax, __shfl_xor(pmax, 32));
    const float m_new = fmaxf(m_run, pmax);
    const float corr  = exp2f(m_run - m_new);
    float p0[16], p1[16];
    float psum = 0.f;
    #pragma unroll
    for (int r = 0; r < 16; ++r) { p0[r] = exp2f(st0[r] - m_new); psum += p0[r]; }
    #pragma unroll
    for (int r = 0; r < 16; ++r) { p1[r] = exp2f(st1[r] - m_new); psum += p1[r]; }
    psum += __shfl_xor(psum, 32);
    l_run = l_run * corr + psum;
    m_run = m_new;
    #pragma unroll
    for (int dt = 0; dt < 4; ++dt) oacc[dt] = oacc[dt] * corr;

    // ---- pack P fragments: pf[c].u[j] = p[c>>1][8*(c&1)+j]
    //      (k-convention κ(hi,j) = (j&3)+4hi+8(j>>2), matching st C/D layout)
    bf16x8 pf[4];
    #pragma unroll
    for (int c = 0; c < 4; ++c) {
      union { bf16x8 v; unsigned short u[8]; } f;
      #pragma unroll
      for (int j = 0; j < 8; ++j)
        f.u[j] = f2bf((c & 2) ? p1[8 * (c & 1) + j] : p0[8 * (c & 1) + j]);
      pf[c] = f.v;
    }

    // ---- PV: O^T (128 d x 32 q) += V^T * P, K dim = 64 kv (4 chunks of 16).
    const int swv = (l31 & 15) << 3;
    #pragma unroll
    for (int c = 0; c < 4; ++c) {
      #pragma unroll
      for (int dt = 0; dt < 4; ++dt) {
        const char* vb = smV + (dt * 32 + l31) * 128;
        union { bf16x8 v; u16x4 h[2]; } a;
        a.h[0] = *reinterpret_cast<const u16x4*>(vb + ((c * 32 + 8 * hi) ^ swv));
        a.h[1] = *reinterpret_cast<const u16x4*>(vb + ((c * 32 + 16 + 8 * hi) ^ swv));
        oacc[dt] = __builtin_amdgcn_mfma_f32_32x32x16_bf16(a.v, pf[c], oacc[dt], 0, 0, 0);
      }
    }

    __syncthreads();   // drains next-tile DMA + everyone done reading smem[cur]
    cur ^= 1;
  }
#undef STAGE

  // ---- epilogue. O^T C/D layout: d = dt*32 + 8*rg + 4*hi + (r&3), col q.
  const float inv = (ksplit == 1) ? (1.f / l_run) : 1.f;
  float* dst = (ksplit == 1) ? Od : (Od + (size_t)chunk * NTOK * DH);
  #pragma unroll
  for (int dt = 0; dt < 4; ++dt) {
    #pragma unroll
    for (int rg = 0; rg < 4; ++rg) {
      const int d0 = dt * 32 + rg * 8 + hi * 4;
      float4 o;
      o.x = oacc[dt][rg * 4 + 0] * inv; o.y = oacc[dt][rg * 4 + 1] * inv;
      o.z = oacc[dt][rg * 4 + 2] * inv; o.w = oacc[dt][rg * 4 + 3] * inv;
      *reinterpret_cast<float4*>(dst + (size_t)q * DH + d0) = o;
    }
  }
  if (ksplit > 1 && hi == 0) {
    Mp[chunk * NTOK + q] = m_run;
    Lp[chunk * NTOK + q] = l_run;
  }
}

__global__ __launch_bounds__(256)
void fa_combine(const float* __restrict__ Op, const float* __restrict__ Mp,
                const float* __restrict__ Lp, float* __restrict__ out, int ksplit)
{
  const int gid = blockIdx.x * 256 + threadIdx.x;   // N*D/4 threads
  const int q   = gid >> 5;
  const int dv  = (gid & 31) * 4;
  float mx = -INFINITY;
  for (int c = 0; c < ksplit; ++c) mx = fmaxf(mx, Mp[c * NTOK + q]);
  float den = 0.f;
  float ax = 0.f, ay = 0.f, az = 0.f, aw = 0.f;
  for (int c = 0; c < ksplit; ++c) {
    const float w = exp2f(Mp[c * NTOK + q] - mx);
    den += w * Lp[c * NTOK + q];
    float4 o = *reinterpret_cast<const float4*>(Op + (size_t)c * NTOK * DH + (size_t)q * DH + dv);
    ax += w * o.x; ay += w * o.y; az += w * o.z; aw += w * o.w;
  }
  const float r = 1.f / den;
  float4 res; res.x = ax * r; res.y = ay * r; res.z = az * r; res.w = aw * r;
  *reinterpret_cast<float4*>(out + (size_t)q * DH + dv) = res;
}

extern "C" void kernel_launch(void* const* d_in, const int* in_sizes, int n_in,
                              void* d_out, int out_size, void* d_ws, size_t ws_size,
                              hipStream_t stream)
{
  const float* Q = (const float*)d_in[0];
  const float* K = (const float*)d_in[1];
  const float* V = (const float*)d_in[2];
  float* out = (float*)d_out;

  auto need = [](size_t ks) {
    return ks * (size_t)NTOK * DH * 4 + 2 * ks * (size_t)NTOK * 4;
  };
  // Round-1 evidence: ws_size >= need(4) (KS=4 ran). Prefer 8 for occupancy.
  int KS = (ws_size >= need(8)) ? 8 : (ws_size >= need(4)) ? 4 : 2;

  // K/V bf16 images live in d_out (exactly 4 MiB = out bytes); the combine
  // pass overwrites d_out afterwards. Stream-ordered: prep -> fwd -> combine.
  char* Kimg = (char*)d_out;
  char* Vimg = Kimg + (size_t)NTOK * 256;          // 2 MiB each

  float* Op = (float*)d_ws;
  float* Mp = Op + (size_t)KS * NTOK * DH;
  float* Lp = Mp + (size_t)KS * NTOK;

  fa_prep<<<NTOK / KVB, 256, 0, stream>>>(K, V, Kimg, Vimg);
  fa_fwd<<<dim3(NTOK / QBLK, KS), 256, 0, stream>>>(Q, Kimg, Vimg, Op, Mp, Lp,
                                                    KS, NTOK / KS);
  fa_combine<<<NTOK * DH / 4 / 256, 256, 0, stream>>>(Op, Mp, Lp, out, KS);
}

// Round 3
// 78.197 us; speedup vs baseline: 2.1702x; 1.0186x over previous
//
#include <hip/hip_runtime.h>

#define NTOK 8192
#define DH   128
#define QBLK 128
#define KVB  64

typedef __attribute__((ext_vector_type(8)))  short bf16x8;
typedef __attribute__((ext_vector_type(16))) float f32x16;
typedef __attribute__((ext_vector_type(4)))  unsigned short u16x4;

typedef __attribute__((address_space(1))) const void gv_t;
typedef __attribute__((address_space(3))) void sv_t;

static __device__ __forceinline__ unsigned short f2bf(float x) {
  union { float f; unsigned int u; } a; a.f = x;
  unsigned int r = a.u + 0x7FFFu + ((a.u >> 16) & 1u);  // RNE
  return (unsigned short)(r >> 16);
}

static __device__ __forceinline__ unsigned pk2(float lo, float hi) {
  unsigned r;
  asm("v_cvt_pk_bf16_f32 %0, %1, %2" : "=v"(r) : "v"(lo), "v"(hi));
  return r;
}

static __device__ __forceinline__ f32x16 zero16() {
  f32x16 v;
  #pragma unroll
  for (int i = 0; i < 16; ++i) v[i] = 0.f;
  return v;
}

// ---------------------------------------------------------------------------
// Pre-pass: bf16 "LDS images" of K (row-major, swizzle (row&15)<<4 @16B) and
// V^T (128 d-rows x 128B, swizzle (d&15)<<3 @8B), tiled by 64 kv (16KB/tile).
// ---------------------------------------------------------------------------
__global__ __launch_bounds__(256)
void fa_prep(const float* __restrict__ Kg, const float* __restrict__ Vg,
             char* __restrict__ Kimg, char* __restrict__ Vimg)
{
  const int t = blockIdx.x;
  const int tid = threadIdx.x;

  { // K tile: 64 rows x 256B
    const int krow = tid >> 2;
    const int kcg  = (tid & 3) * 32;
    const float* src = Kg + ((size_t)t * KVB + krow) * DH + kcg;
    char* drow = Kimg + (size_t)t * 16384 + krow * 256;
    const int sw = (krow & 15) << 4;
    #pragma unroll
    for (int w = 0; w < 4; ++w) {
      float4 a = *reinterpret_cast<const float4*>(src + w * 8);
      float4 b = *reinterpret_cast<const float4*>(src + w * 8 + 4);
      union { bf16x8 v; unsigned short u[8]; } f;
      f.u[0] = f2bf(a.x); f.u[1] = f2bf(a.y); f.u[2] = f2bf(a.z); f.u[3] = f2bf(a.w);
      f.u[4] = f2bf(b.x); f.u[5] = f2bf(b.y); f.u[6] = f2bf(b.z); f.u[7] = f2bf(b.w);
      *reinterpret_cast<bf16x8*>(drow + ((kcg * 2 + w * 16) ^ sw)) = f.v;
    }
  }

  { // V^T tile: 128 d-rows x 128B, 4x4 register transpose per task
    #pragma unroll
    for (int it = 0; it < 2; ++it) {
      int task = tid + it * 256;            // 512 tasks of 4kv x 4d
      int kvl  = (task & 15) * 4;
      int d0   = (task >> 4) * 4;
      const float* src = Vg + ((size_t)t * KVB + kvl) * DH + d0;
      float4 r0 = *reinterpret_cast<const float4*>(src);
      float4 r1 = *reinterpret_cast<const float4*>(src + DH);
      float4 r2 = *reinterpret_cast<const float4*>(src + 2 * DH);
      float4 r3 = *reinterpret_cast<const float4*>(src + 3 * DH);
      char* base = Vimg + (size_t)t * 16384;
      const int bb = kvl * 2;
      { int d = d0 + 0;
        u16x4 w4 = (u16x4){f2bf(r0.x), f2bf(r1.x), f2bf(r2.x), f2bf(r3.x)};
        *reinterpret_cast<u16x4*>(base + d * 128 + (bb ^ ((d & 15) << 3))) = w4; }
      { int d = d0 + 1;
        u16x4 w4 = (u16x4){f2bf(r0.y), f2bf(r1.y), f2bf(r2.y), f2bf(r3.y)};
        *reinterpret_cast<u16x4*>(base + d * 128 + (bb ^ ((d & 15) << 3))) = w4; }
      { int d = d0 + 2;
        u16x4 w4 = (u16x4){f2bf(r0.z), f2bf(r1.z), f2bf(r2.z), f2bf(r3.z)};
        *reinterpret_cast<u16x4*>(base + d * 128 + (bb ^ ((d & 15) << 3))) = w4; }
      { int d = d0 + 3;
        u16x4 w4 = (u16x4){f2bf(r0.w), f2bf(r1.w), f2bf(r2.w), f2bf(r3.w)};
        *reinterpret_cast<u16x4*>(base + d * 128 + (bb ^ ((d & 15) << 3))) = w4; }
    }
  }
}

// ---------------------------------------------------------------------------
// softmax over one 32-kv half: defer-max online update + fused exp->cvt_pk.
// pfa.u[j] = P[kv j], pfb.u[j] = P[kv 8+j]  (k-convention of the PV MFMA).
// ---------------------------------------------------------------------------
static __device__ __forceinline__ void softmax_half(
    const f32x16& st, float& m_run, float& l_run, f32x16* oacc,
    bf16x8& pfa, bf16x8& pfb)
{
  float pmax = st[0];
  #pragma unroll
  for (int r = 1; r < 16; ++r) pmax = fmaxf(pmax, st[r]);
  pmax = fmaxf(pmax, __shfl_xor(pmax, 32));
  if (!__all(pmax <= m_run + 8.f)) {            // rare after warm-up (T13)
    const float m_new = fmaxf(m_run, pmax);
    const float corr  = (m_run > -1e30f) ? exp2f(m_run - m_new) : 0.f;
    l_run *= corr;
    #pragma unroll
    for (int i = 0; i < 4; ++i) oacc[i] = oacc[i] * corr;
    m_run = m_new;
  }
  float psum = 0.f;
  unsigned w[8];
  #pragma unroll
  for (int i = 0; i < 8; ++i) {
    const float e0 = exp2f(st[2 * i]     - m_run);
    const float e1 = exp2f(st[2 * i + 1] - m_run);
    psum += e0 + e1;
    w[i] = pk2(e0, e1);                          // bf16 pair, RNE
  }
  psum += __shfl_xor(psum, 32);
  l_run += psum;
  union { bf16x8 v; unsigned u[4]; } fa, fb;
  fa.u[0] = w[0]; fa.u[1] = w[1]; fa.u[2] = w[2]; fa.u[3] = w[3];
  fb.u[0] = w[4]; fb.u[1] = w[5]; fb.u[2] = w[6]; fb.u[3] = w[7];
  pfa = fa.v; pfb = fb.v;
}

// ---------------------------------------------------------------------------
// Flash fwd: 4 waves x 32 q (QBLK=128), 32x32x16 MFMA, double-buffered DMA,
// split-half pipeline: QK0,QK1 | sm0 (|| QK1 in pipe) | PV0 | sm1 (|| PV0) | PV1.
// ---------------------------------------------------------------------------
__global__ __launch_bounds__(256, 2)
void fa_fwd(const float* __restrict__ Qg, const char* __restrict__ Kimg,
            const char* __restrict__ Vimg, float* __restrict__ Od,
            float* __restrict__ Mp, float* __restrict__ Lp,
            int ksplit, int chunk_len)
{
  __shared__ __align__(16) char smem[2][32768];   // [buf][K 16KB | V 16KB]
  const int tid  = threadIdx.x;
  const int lane = tid & 63;
  const int wv   = tid >> 6;
  const int l31  = lane & 31;
  const int hi   = lane >> 5;

  const int q     = blockIdx.x * QBLK + wv * 32 + l31;
  const int chunk = blockIdx.y;
  const float QSCALE = 0.1275313310087464f;       // rsqrt(128) * log2(e)

  const int tile0 = (chunk * chunk_len) >> 6;
  const int nst   = chunk_len >> 6;

  // Per-wave DMA roles: waves 0,1 = K halves; waves 2,3 = V halves (8KB each).
  const char* gbase = (wv < 2 ? Kimg : Vimg);
  const size_t goff = (size_t)(wv & 1) * 8192 + (size_t)lane * 16;
  const int    loff = (wv < 2 ? 0 : 16384) + (wv & 1) * 8192;

#define STAGE(B, T) do {                                                      \
    const char* _s = gbase + (size_t)(T) * 16384 + goff;                      \
    char* _d = &smem[B][loff];                                                \
    _Pragma("unroll")                                                         \
    for (int _i = 0; _i < 8; ++_i)                                            \
      __builtin_amdgcn_global_load_lds((gv_t*)(_s + _i * 1024),               \
                                       (sv_t*)(_d + _i * 1024), 16, 0, 0);    \
  } while (0)

  STAGE(0, tile0);

  // Q fragments: qf[kc] holds Q[q][kc*16 + hi*8 + j], pre-scaled.
  bf16x8 qf[8];
  {
    const float* qs = Qg + (size_t)q * DH + hi * 8;
    #pragma unroll
    for (int kc = 0; kc < 8; ++kc) {
      float4 a = *reinterpret_cast<const float4*>(qs + kc * 16);
      float4 b = *reinterpret_cast<const float4*>(qs + kc * 16 + 4);
      union { bf16x8 v; unsigned u[4]; } f;
      f.u[0] = pk2(a.x * QSCALE, a.y * QSCALE);
      f.u[1] = pk2(a.z * QSCALE, a.w * QSCALE);
      f.u[2] = pk2(b.x * QSCALE, b.y * QSCALE);
      f.u[3] = pk2(b.z * QSCALE, b.w * QSCALE);
      qf[kc] = f.v;
    }
  }

  f32x16 oacc[4];
  #pragma unroll
  for (int i = 0; i < 4; ++i) oacc[i] = zero16();
  float m_run = -INFINITY, l_run = 0.f;

  __syncthreads();                                 // tile 0 staged

  int cur = 0;
  for (int t = 0; t < nst; ++t) {
    if (t + 1 < nst) STAGE(cur ^ 1, tile0 + t + 1);   // in flight during compute

    const char* smK = smem[cur];
    const char* smV = smem[cur] + 16384;
    const int swk = (l31 & 15) << 4;
    const int swv = (l31 & 15) << 3;

    // ---- QK^T both halves (two independent MFMA chains fill the pipe)
    f32x16 st0 = zero16(), st1 = zero16();
    #pragma unroll
    for (int kc = 0; kc < 8; ++kc) {
      const int cb = (kc * 32 + hi * 16) ^ swk;
      bf16x8 a0 = *reinterpret_cast<const bf16x8*>(smK + l31 * 256 + cb);
      st0 = __builtin_amdgcn_mfma_f32_32x32x16_bf16(a0, qf[kc], st0, 0, 0, 0);
      bf16x8 a1 = *reinterpret_cast<const bf16x8*>(smK + (l31 + 32) * 256 + cb);
      st1 = __builtin_amdgcn_mfma_f32_32x32x16_bf16(a1, qf[kc], st1, 0, 0, 0);
    }

    // ---- half 0: softmax (VALU, overlaps st1 MFMAs) then PV kv 0..31
    bf16x8 pf0a, pf0b;
    softmax_half(st0, m_run, l_run, oacc, pf0a, pf0b);
    #pragma unroll
    for (int c = 0; c < 2; ++c) {
      const bf16x8 pb = c ? pf0b : pf0a;
      #pragma unroll
      for (int dt = 0; dt < 4; ++dt) {
        const char* vb = smV + (dt * 32 + l31) * 128;
        union { bf16x8 v; u16x4 h[2]; } a;
        a.h[0] = *reinterpret_cast<const u16x4*>(vb + ((c * 32 + 8 * hi) ^ swv));
        a.h[1] = *reinterpret_cast<const u16x4*>(vb + ((c * 32 + 16 + 8 * hi) ^ swv));
        oacc[dt] = __builtin_amdgcn_mfma_f32_32x32x16_bf16(a.v, pb, oacc[dt], 0, 0, 0);
      }
    }

    // ---- half 1: softmax (overlaps PV0 MFMAs) then PV kv 32..63
    bf16x8 pf1a, pf1b;
    softmax_half(st1, m_run, l_run, oacc, pf1a, pf1b);
    #pragma unroll
    for (int c = 2; c < 4; ++c) {
      const bf16x8 pb = (c & 1) ? pf1b : pf1a;
      #pragma unroll
      for (int dt = 0; dt < 4; ++dt) {
        const char* vb = smV + (dt * 32 + l31) * 128;
        union { bf16x8 v; u16x4 h[2]; } a;
        a.h[0] = *reinterpret_cast<const u16x4*>(vb + ((c * 32 + 8 * hi) ^ swv));
        a.h[1] = *reinterpret_cast<const u16x4*>(vb + ((c * 32 + 16 + 8 * hi) ^ swv));
        oacc[dt] = __builtin_amdgcn_mfma_f32_32x32x16_bf16(a.v, pb, oacc[dt], 0, 0, 0);
      }
    }

    __syncthreads();   // drains next-tile DMA; smem[cur] free
    cur ^= 1;
  }
#undef STAGE

  // ---- epilogue: transpose O^T -> [q][d] via per-wave 16KB LDS, then
  //      fully-coalesced row stores (fixes the 2.2x write amplification).
  char* base = &smem[0][0] + wv * 16384;           // [d][q] f32, 128B rows
  const float scale = (ksplit == 1) ? (1.f / l_run) : 1.f;
  #pragma unroll
  for (int dt = 0; dt < 4; ++dt)
    #pragma unroll
    for (int rg = 0; rg < 4; ++rg)
      #pragma unroll
      for (int j = 0; j < 4; ++j) {
        const int d = dt * 32 + rg * 8 + hi * 4 + j;
        *reinterpret_cast<float*>(base + d * 128 + l31 * 4) =
            oacc[dt][rg * 4 + j] * scale;
      }
  // per-wave region: no block barrier needed (lgkmcnt ordering within wave)
  const int qloc = lane >> 1;
  const int dh   = lane & 1;
  float* dst = ((ksplit == 1) ? Od : Od + (size_t)chunk * NTOK * DH)
               + (size_t)(blockIdx.x * QBLK + wv * 32 + qloc) * DH + dh * 64;
  #pragma unroll
  for (int i4 = 0; i4 < 16; ++i4) {
    float4 v;
    v.x = *reinterpret_cast<float*>(base + (dh * 64 + i4 * 4 + 0) * 128 + qloc * 4);
    v.y = *reinterpret_cast<float*>(base + (dh * 64 + i4 * 4 + 1) * 128 + qloc * 4);
    v.z = *reinterpret_cast<float*>(base + (dh * 64 + i4 * 4 + 2) * 128 + qloc * 4);
    v.w = *reinterpret_cast<float*>(base + (dh * 64 + i4 * 4 + 3) * 128 + qloc * 4);
    *reinterpret_cast<float4*>(dst + i4 * 4) = v;
  }
  if (ksplit > 1 && lane < 32) {
    const int qg = blockIdx.x * QBLK + wv * 32 + lane;
    Mp[chunk * NTOK + qg] = m_run;
    Lp[chunk * NTOK + qg] = l_run;
  }
}

__global__ __launch_bounds__(256)
void fa_combine(const float* __restrict__ Op, const float* __restrict__ Mp,
                const float* __restrict__ Lp, float* __restrict__ out, int ksplit)
{
  const int gid = blockIdx.x * 256 + threadIdx.x;   // N*D/4 threads
  const int q   = gid >> 5;
  const int dv  = (gid & 31) * 4;
  float mx = -INFINITY;
  for (int c = 0; c < ksplit; ++c) mx = fmaxf(mx, Mp[c * NTOK + q]);
  float den = 0.f;
  float ax = 0.f, ay = 0.f, az = 0.f, aw = 0.f;
  for (int c = 0; c < ksplit; ++c) {
    const float w = exp2f(Mp[c * NTOK + q] - mx);
    den += w * Lp[c * NTOK + q];
    float4 o = *reinterpret_cast<const float4*>(Op + (size_t)c * NTOK * DH + (size_t)q * DH + dv);
    ax += w * o.x; ay += w * o.y; az += w * o.z; aw += w * o.w;
  }
  const float r = 1.f / den;
  float4 res; res.x = ax * r; res.y = ay * r; res.z = az * r; res.w = aw * r;
  *reinterpret_cast<float4*>(out + (size_t)q * DH + dv) = res;
}

extern "C" void kernel_launch(void* const* d_in, const int* in_sizes, int n_in,
                              void* d_out, int out_size, void* d_ws, size_t ws_size,
                              hipStream_t stream)
{
  const float* Q = (const float*)d_in[0];
  const float* K = (const float*)d_in[1];
  const float* V = (const float*)d_in[2];
  float* out = (float*)d_out;

  auto need = [](size_t ks) {
    return ks * (size_t)NTOK * DH * 4 + 2 * ks * (size_t)NTOK * 4;
  };
  int KS = (ws_size >= need(8)) ? 8 : (ws_size >= need(4)) ? 4 : 2;

  // K/V bf16 images live in d_out (4 MiB); combine overwrites d_out at the end.
  char* Kimg = (char*)d_out;
  char* Vimg = Kimg + (size_t)NTOK * 256;          // 2 MiB each

  float* Op = (float*)d_ws;
  float* Mp = Op + (size_t)KS * NTOK * DH;
  float* Lp = Mp + (size_t)KS * NTOK;

  fa_prep<<<NTOK / KVB, 256, 0, stream>>>(K, V, Kimg, Vimg);
  fa_fwd<<<dim3(NTOK / QBLK, KS), 256, 0, stream>>>(Q, Kimg, Vimg, Op, Mp, Lp,
                                                    KS, NTOK / KS);
  fa_combine<<<NTOK * DH / 4 / 256, 256, 0, stream>>>(Op, Mp, Lp, out, KS);
}

// Round 4
// 75.329 us; speedup vs baseline: 2.2528x; 1.0381x over previous
//
#include <hip/hip_runtime.h>

#define NTOK 8192
#define DH   128
#define QBLK 128
#define KVB  64

typedef __attribute__((ext_vector_type(8)))  short bf16x8;
typedef __attribute__((ext_vector_type(16))) float f32x16;
typedef __attribute__((ext_vector_type(4)))  unsigned short u16x4;

typedef __attribute__((address_space(1))) const void gv_t;
typedef __attribute__((address_space(3))) void sv_t;

static __device__ __forceinline__ unsigned short f2bf(float x) {
  union { float f; unsigned int u; } a; a.f = x;
  unsigned int r = a.u + 0x7FFFu + ((a.u >> 16) & 1u);  // RNE
  return (unsigned short)(r >> 16);
}

static __device__ __forceinline__ unsigned pk2(float lo, float hi) {
  unsigned r;
  asm("v_cvt_pk_bf16_f32 %0, %1, %2" : "=v"(r) : "v"(lo), "v"(hi));
  return r;
}

static __device__ __forceinline__ f32x16 zero16() {
  f32x16 v;
  #pragma unroll
  for (int i = 0; i < 16; ++i) v[i] = 0.f;
  return v;
}

// ---------------------------------------------------------------------------
// Pre-pass: bf16 "LDS images" of K (row-major, swizzle (row&15)<<4 @16B) and
// V^T (128 d-rows x 128B, swizzle (d&15)<<3 @8B), tiled by 64 kv (16KB/tile).
// ---------------------------------------------------------------------------
__global__ __launch_bounds__(256)
void fa_prep(const float* __restrict__ Kg, const float* __restrict__ Vg,
             char* __restrict__ Kimg, char* __restrict__ Vimg)
{
  const int t = blockIdx.x;
  const int tid = threadIdx.x;

  { // K tile: 64 rows x 256B
    const int krow = tid >> 2;
    const int kcg  = (tid & 3) * 32;
    const float* src = Kg + ((size_t)t * KVB + krow) * DH + kcg;
    char* drow = Kimg + (size_t)t * 16384 + krow * 256;
    const int sw = (krow & 15) << 4;
    #pragma unroll
    for (int w = 0; w < 4; ++w) {
      float4 a = *reinterpret_cast<const float4*>(src + w * 8);
      float4 b = *reinterpret_cast<const float4*>(src + w * 8 + 4);
      union { bf16x8 v; unsigned short u[8]; } f;
      f.u[0] = f2bf(a.x); f.u[1] = f2bf(a.y); f.u[2] = f2bf(a.z); f.u[3] = f2bf(a.w);
      f.u[4] = f2bf(b.x); f.u[5] = f2bf(b.y); f.u[6] = f2bf(b.z); f.u[7] = f2bf(b.w);
      *reinterpret_cast<bf16x8*>(drow + ((kcg * 2 + w * 16) ^ sw)) = f.v;
    }
  }

  { // V^T tile: 128 d-rows x 128B, 4x4 register transpose per task
    #pragma unroll
    for (int it = 0; it < 2; ++it) {
      int task = tid + it * 256;            // 512 tasks of 4kv x 4d
      int kvl  = (task & 15) * 4;
      int d0   = (task >> 4) * 4;
      const float* src = Vg + ((size_t)t * KVB + kvl) * DH + d0;
      float4 r0 = *reinterpret_cast<const float4*>(src);
      float4 r1 = *reinterpret_cast<const float4*>(src + DH);
      float4 r2 = *reinterpret_cast<const float4*>(src + 2 * DH);
      float4 r3 = *reinterpret_cast<const float4*>(src + 3 * DH);
      char* base = Vimg + (size_t)t * 16384;
      const int bb = kvl * 2;
      { int d = d0 + 0;
        u16x4 w4 = (u16x4){f2bf(r0.x), f2bf(r1.x), f2bf(r2.x), f2bf(r3.x)};
        *reinterpret_cast<u16x4*>(base + d * 128 + (bb ^ ((d & 15) << 3))) = w4; }
      { int d = d0 + 1;
        u16x4 w4 = (u16x4){f2bf(r0.y), f2bf(r1.y), f2bf(r2.y), f2bf(r3.y)};
        *reinterpret_cast<u16x4*>(base + d * 128 + (bb ^ ((d & 15) << 3))) = w4; }
      { int d = d0 + 2;
        u16x4 w4 = (u16x4){f2bf(r0.z), f2bf(r1.z), f2bf(r2.z), f2bf(r3.z)};
        *reinterpret_cast<u16x4*>(base + d * 128 + (bb ^ ((d & 15) << 3))) = w4; }
      { int d = d0 + 3;
        u16x4 w4 = (u16x4){f2bf(r0.w), f2bf(r1.w), f2bf(r2.w), f2bf(r3.w)};
        *reinterpret_cast<u16x4*>(base + d * 128 + (bb ^ ((d & 15) << 3))) = w4; }
    }
  }
}

// ---------------------------------------------------------------------------
// softmax over one 32-kv half: defer-max online update + fused exp->cvt_pk.
// ---------------------------------------------------------------------------
static __device__ __forceinline__ void softmax_half(
    const f32x16& st, float& m_run, float& l_run, f32x16* oacc,
    bf16x8& pfa, bf16x8& pfb)
{
  float pmax = st[0];
  #pragma unroll
  for (int r = 1; r < 16; ++r) pmax = fmaxf(pmax, st[r]);
  pmax = fmaxf(pmax, __shfl_xor(pmax, 32));
  if (!__all(pmax <= m_run + 8.f)) {            // rare after warm-up (T13)
    const float m_new = fmaxf(m_run, pmax);
    const float corr  = (m_run > -1e30f) ? exp2f(m_run - m_new) : 0.f;
    l_run *= corr;
    #pragma unroll
    for (int i = 0; i < 4; ++i) oacc[i] = oacc[i] * corr;
    m_run = m_new;
  }
  float psum = 0.f;
  unsigned w[8];
  #pragma unroll
  for (int i = 0; i < 8; ++i) {
    const float e0 = exp2f(st[2 * i]     - m_run);
    const float e1 = exp2f(st[2 * i + 1] - m_run);
    psum += e0 + e1;
    w[i] = pk2(e0, e1);                          // bf16 pair, RNE
  }
  psum += __shfl_xor(psum, 32);
  l_run += psum;
  union { bf16x8 v; unsigned u[4]; } fa, fb;
  fa.u[0] = w[0]; fa.u[1] = w[1]; fa.u[2] = w[2]; fa.u[3] = w[3];
  fb.u[0] = w[4]; fb.u[1] = w[5]; fb.u[2] = w[6]; fb.u[3] = w[7];
  pfa = fa.v; pfb = fb.v;
}

// ---------------------------------------------------------------------------
// Flash fwd: 4 waves x 32 q (QBLK=128), 32x32x16 MFMA.
// Depth-2 DMA prefetch + counted vmcnt(8) + raw barriers (no drain in loop).
// ---------------------------------------------------------------------------
__global__ __launch_bounds__(256, 2)
void fa_fwd(const float* __restrict__ Qg, const char* __restrict__ Kimg,
            const char* __restrict__ Vimg, float* __restrict__ Od,
            float* __restrict__ Mp, float* __restrict__ Lp,
            int ksplit, int chunk_len)
{
  __shared__ __align__(16) char smem[2][32768];   // [buf][K 16KB | V 16KB]
  const int tid  = threadIdx.x;
  const int lane = tid & 63;
  const int wv   = tid >> 6;
  const int l31  = lane & 31;
  const int hi   = lane >> 5;

  const int q     = blockIdx.x * QBLK + wv * 32 + l31;
  const int chunk = blockIdx.y;
  const float QSCALE = 0.1275313310087464f;       // rsqrt(128) * log2(e)

  const int tile0 = (chunk * chunk_len) >> 6;
  const int nst   = chunk_len >> 6;

  // ---- Q fragments FIRST (so loop vmcnt counts only DMA loads).
  bf16x8 qf[8];
  {
    const float* qs = Qg + (size_t)q * DH + hi * 8;
    #pragma unroll
    for (int kc = 0; kc < 8; ++kc) {
      float4 a = *reinterpret_cast<const float4*>(qs + kc * 16);
      float4 b = *reinterpret_cast<const float4*>(qs + kc * 16 + 4);
      union { bf16x8 v; unsigned u[4]; } f;
      f.u[0] = pk2(a.x * QSCALE, a.y * QSCALE);
      f.u[1] = pk2(a.z * QSCALE, a.w * QSCALE);
      f.u[2] = pk2(b.x * QSCALE, b.y * QSCALE);
      f.u[3] = pk2(b.z * QSCALE, b.w * QSCALE);
      qf[kc] = f.v;
    }
  }

  // Per-wave DMA roles: waves 0,1 = K halves; waves 2,3 = V halves (8KB each,
  // 8 x 1KB global_load_lds_dwordx4 per wave per tile).
  const char* gbase = (wv < 2 ? Kimg : Vimg);
  const size_t goff = (size_t)(wv & 1) * 8192 + (size_t)lane * 16;
  const int    loff = (wv < 2 ? 0 : 16384) + (wv & 1) * 8192;

#define STAGE(B, T) do {                                                      \
    const char* _s = gbase + (size_t)(T) * 16384 + goff;                      \
    char* _d = &smem[B][loff];                                                \
    _Pragma("unroll")                                                         \
    for (int _i = 0; _i < 8; ++_i)                                            \
      __builtin_amdgcn_global_load_lds((gv_t*)(_s + _i * 1024),               \
                                       (sv_t*)(_d + _i * 1024), 16, 0, 0);    \
  } while (0)

  STAGE(0, tile0);
  if (nst > 1) STAGE(1, tile0 + 1);

  f32x16 oacc[4];
  #pragma unroll
  for (int i = 0; i < 4; ++i) oacc[i] = zero16();
  float m_run = -INFINITY, l_run = 0.f;

  int cur = 0;
  for (int t = 0; t < nst; ++t) {
    // tile t's own 8 DMA loads done; tile t+1's 8 stay in flight (T4).
    if (t + 1 < nst) asm volatile("s_waitcnt vmcnt(8)" ::: "memory");
    else             asm volatile("s_waitcnt vmcnt(0)" ::: "memory");
    __builtin_amdgcn_sched_barrier(0);
    __builtin_amdgcn_s_barrier();          // cross-wave: tile t fully in LDS

    const char* smK = smem[cur];
    const char* smV = smem[cur] + 16384;
    const int swk = (l31 & 15) << 4;
    const int swv = (l31 & 15) << 3;

    // ---- QK^T both halves (two independent MFMA chains)
    f32x16 st0 = zero16(), st1 = zero16();
    __builtin_amdgcn_s_setprio(1);
    #pragma unroll
    for (int kc = 0; kc < 8; ++kc) {
      const int cb = (kc * 32 + hi * 16) ^ swk;
      bf16x8 a0 = *reinterpret_cast<const bf16x8*>(smK + l31 * 256 + cb);
      st0 = __builtin_amdgcn_mfma_f32_32x32x16_bf16(a0, qf[kc], st0, 0, 0, 0);
      bf16x8 a1 = *reinterpret_cast<const bf16x8*>(smK + (l31 + 32) * 256 + cb);
      st1 = __builtin_amdgcn_mfma_f32_32x32x16_bf16(a1, qf[kc], st1, 0, 0, 0);
    }
    __builtin_amdgcn_s_setprio(0);

    // ---- half 0: softmax (VALU, overlaps st1 MFMAs) then PV kv 0..31
    bf16x8 pf0a, pf0b;
    softmax_half(st0, m_run, l_run, oacc, pf0a, pf0b);
    __builtin_amdgcn_s_setprio(1);
    #pragma unroll
    for (int c = 0; c < 2; ++c) {
      const bf16x8 pb = c ? pf0b : pf0a;
      #pragma unroll
      for (int dt = 0; dt < 4; ++dt) {
        const char* vb = smV + (dt * 32 + l31) * 128;
        union { bf16x8 v; u16x4 h[2]; } a;
        a.h[0] = *reinterpret_cast<const u16x4*>(vb + ((c * 32 + 8 * hi) ^ swv));
        a.h[1] = *reinterpret_cast<const u16x4*>(vb + ((c * 32 + 16 + 8 * hi) ^ swv));
        oacc[dt] = __builtin_amdgcn_mfma_f32_32x32x16_bf16(a.v, pb, oacc[dt], 0, 0, 0);
      }
    }
    __builtin_amdgcn_s_setprio(0);

    // ---- half 1: softmax (overlaps PV0 MFMAs) then PV kv 32..63
    bf16x8 pf1a, pf1b;
    softmax_half(st1, m_run, l_run, oacc, pf1a, pf1b);
    __builtin_amdgcn_s_setprio(1);
    #pragma unroll
    for (int c = 2; c < 4; ++c) {
      const bf16x8 pb = (c & 1) ? pf1b : pf1a;
      #pragma unroll
      for (int dt = 0; dt < 4; ++dt) {
        const char* vb = smV + (dt * 32 + l31) * 128;
        union { bf16x8 v; u16x4 h[2]; } a;
        a.h[0] = *reinterpret_cast<const u16x4*>(vb + ((c * 32 + 8 * hi) ^ swv));
        a.h[1] = *reinterpret_cast<const u16x4*>(vb + ((c * 32 + 16 + 8 * hi) ^ swv));
        oacc[dt] = __builtin_amdgcn_mfma_f32_32x32x16_bf16(a.v, pb, oacc[dt], 0, 0, 0);
      }
    }
    __builtin_amdgcn_s_setprio(0);

    __builtin_amdgcn_s_barrier();          // all waves done reading buf[cur]
    if (t + 2 < nst) STAGE(cur, tile0 + t + 2);   // refill freed buffer
    cur ^= 1;
  }
#undef STAGE

  // ---- epilogue: transpose O^T -> [q][d] via per-wave 16KB LDS, then
  //      coalesced row stores.
  char* base = &smem[0][0] + wv * 16384;           // [d][q] f32, 128B rows
  const float scale = (ksplit == 1) ? (1.f / l_run) : 1.f;
  #pragma unroll
  for (int dt = 0; dt < 4; ++dt)
    #pragma unroll
    for (int rg = 0; rg < 4; ++rg)
      #pragma unroll
      for (int j = 0; j < 4; ++j) {
        const int d = dt * 32 + rg * 8 + hi * 4 + j;
        *reinterpret_cast<float*>(base + d * 128 + l31 * 4) =
            oacc[dt][rg * 4 + j] * scale;
      }
  const int qloc = lane >> 1;
  const int dh   = lane & 1;
  float* dst = ((ksplit == 1) ? Od : Od + (size_t)chunk * NTOK * DH)
               + (size_t)(blockIdx.x * QBLK + wv * 32 + qloc) * DH + dh * 64;
  #pragma unroll
  for (int i4 = 0; i4 < 16; ++i4) {
    float4 v;
    v.x = *reinterpret_cast<float*>(base + (dh * 64 + i4 * 4 + 0) * 128 + qloc * 4);
    v.y = *reinterpret_cast<float*>(base + (dh * 64 + i4 * 4 + 1) * 128 + qloc * 4);
    v.z = *reinterpret_cast<float*>(base + (dh * 64 + i4 * 4 + 2) * 128 + qloc * 4);
    v.w = *reinterpret_cast<float*>(base + (dh * 64 + i4 * 4 + 3) * 128 + qloc * 4);
    *reinterpret_cast<float4*>(dst + i4 * 4) = v;
  }
  if (ksplit > 1 && lane < 32) {
    const int qg = blockIdx.x * QBLK + wv * 32 + lane;
    Mp[chunk * NTOK + qg] = m_run;
    Lp[chunk * NTOK + qg] = l_run;
  }
}

__global__ __launch_bounds__(256)
void fa_combine(const float* __restrict__ Op, const float* __restrict__ Mp,
                const float* __restrict__ Lp, float* __restrict__ out, int ksplit)
{
  const int gid = blockIdx.x * 256 + threadIdx.x;   // N*D/4 threads
  const int q   = gid >> 5;
  const int dv  = (gid & 31) * 4;
  float mx = -INFINITY;
  for (int c = 0; c < ksplit; ++c) mx = fmaxf(mx, Mp[c * NTOK + q]);
  float den = 0.f;
  float ax = 0.f, ay = 0.f, az = 0.f, aw = 0.f;
  for (int c = 0; c < ksplit; ++c) {
    const float w = exp2f(Mp[c * NTOK + q] - mx);
    den += w * Lp[c * NTOK + q];
    float4 o = *reinterpret_cast<const float4*>(Op + (size_t)c * NTOK * DH + (size_t)q * DH + dv);
    ax += w * o.x; ay += w * o.y; az += w * o.z; aw += w * o.w;
  }
  const float r = 1.f / den;
  float4 res; res.x = ax * r; res.y = ay * r; res.z = az * r; res.w = aw * r;
  *reinterpret_cast<float4*>(out + (size_t)q * DH + dv) = res;
}

extern "C" void kernel_launch(void* const* d_in, const int* in_sizes, int n_in,
                              void* d_out, int out_size, void* d_ws, size_t ws_size,
                              hipStream_t stream)
{
  const float* Q = (const float*)d_in[0];
  const float* K = (const float*)d_in[1];
  const float* V = (const float*)d_in[2];
  float* out = (float*)d_out;

  auto need = [](size_t ks) {
    return ks * (size_t)NTOK * DH * 4 + 2 * ks * (size_t)NTOK * 4;
  };
  int KS = (ws_size >= need(8)) ? 8 : (ws_size >= need(4)) ? 4 : 2;

  // K/V bf16 images live in d_out (4 MiB); combine overwrites d_out at the end.
  char* Kimg = (char*)d_out;
  char* Vimg = Kimg + (size_t)NTOK * 256;          // 2 MiB each

  float* Op = (float*)d_ws;
  float* Mp = Op + (size_t)KS * NTOK * DH;
  float* Lp = Mp + (size_t)KS * NTOK;

  fa_prep<<<NTOK / KVB, 256, 0, stream>>>(K, V, Kimg, Vimg);
  fa_fwd<<<dim3(NTOK / QBLK, KS), 256, 0, stream>>>(Q, Kimg, Vimg, Op, Mp, Lp,
                                                    KS, NTOK / KS);
  fa_combine<<<NTOK * DH / 4 / 256, 256, 0, stream>>>(Op, Mp, Lp, out, KS);
}